// Round 10
// baseline (210.758 us; speedup 1.0000x reference)
//
#include <hip/hip_runtime.h>

#define NN 4096
#define F_IN 1024
#define NHEAD 8
#define HID 64
#define NCLS 40
#define LOG2E 1.44269504f

typedef float f32x4 __attribute__((ext_vector_type(4)));
typedef float f32x2 __attribute__((ext_vector_type(2)));
typedef short s16x8 __attribute__((ext_vector_type(8)));

// XOR-swizzled halfword index within a [R][64]-hw (128B-row) LDS tile:
// byte ^= (row&7)<<4  ->  halfword col ^= (row&7)<<3. 16B-chunk bijective per row.
#define SWZ(r,c) (((r)*64) + ((c) ^ (((r)&7)<<3)))

__device__ __forceinline__ unsigned short f2bf(float f){  // RNE float->bf16
  unsigned u = __float_as_uint(f);
  return (unsigned short)((u + 0x7fffu + ((u >> 16) & 1u)) >> 16);
}
__device__ __forceinline__ unsigned cvtpk(float lo, float hi){  // packed bf16 pair
  unsigned r; asm("v_cvt_pk_bf16_f32 %0, %1, %2" : "=v"(r) : "v"(lo), "v"(hi)); return r;
}
__device__ __forceinline__ f32x2 pkmul(f32x2 a, f32x2 b){  // packed fp32 dual mul
  f32x2 r; asm("v_pk_mul_f32 %0, %1, %2" : "=v"(r) : "v"(a), "v"(b)); return r;
}

// ---------------- pack adjacency -> word-transposed bitmask ----------------
__global__ __launch_bounds__(256) void pack_adj_k(const int* __restrict__ adj, unsigned* __restrict__ bmT){
  int gid = blockIdx.x*256 + threadIdx.x;
  int lane = threadIdx.x & 63;
  unsigned long long m = __ballot(adj[gid] > 0);
  int w = gid >> 5, i = w >> 7, jw = w & 127;
  if (lane == 0)       bmT[(size_t)jw*NN + i] = (unsigned)m;
  else if (lane == 32) bmT[(size_t)jw*NN + i] = (unsigned)(m >> 32);
}

// ---------------- WbT[h][o][k] = bf16(W[h][k][o]) ----------------
__global__ __launch_bounds__(256) void cast_W_k(const float* __restrict__ W, unsigned short* __restrict__ WbT){
  __shared__ float T[64][65];
  const int h = blockIdx.y, k0 = blockIdx.x*64, t = threadIdx.x;
  for (int idx = t; idx < 1024; idx += 256){
    int k = idx >> 4, c4 = idx & 15;
    *(float4*)&T[k][c4*4] = *(const float4*)&W[((size_t)h*F_IN + k0 + k)*HID + c4*4];
  }
  __syncthreads();
  for (int idx = t; idx < 512; idx += 256){
    int o = idx >> 3, ch = idx & 7;
    s16x8 v;
    #pragma unroll
    for (int e = 0; e < 8; ++e) v[e] = (short)f2bf(T[ch*8 + e][o]);
    *(s16x8*)&WbT[((size_t)h*HID + o)*F_IN + k0 + ch*8] = v;
  }
}

// ---------------- WoT[c][k] = bf16(W_out[k][c]), rows 40..47 zero ----------------
__global__ __launch_bounds__(256) void cast_Wo_k(const float* __restrict__ Wout, unsigned short* __restrict__ WoT){
  int idx = blockIdx.x*256 + threadIdx.x;   // 48*512
  int cc = idx >> 9, k = idx & 511;
  WoT[idx] = (cc < NCLS) ? f2bf(Wout[(size_t)k*NCLS + cc]) : (unsigned short)0;
}

// ---------------- gemm1: WhT[h][o][n] bf16 = (x@W)^T ; srcv/dstv fused epilogue ----------------
__global__ __launch_bounds__(256) void gemm1_k(const float* __restrict__ x,
    const unsigned short* __restrict__ WbT, unsigned short* __restrict__ WhT,
    const float* __restrict__ a_src, const float* __restrict__ a_dst,
    float* __restrict__ srcv, float* __restrict__ dstv){
  __shared__ unsigned short xS[64*64];
  __shared__ unsigned short wS[64*64];
  const int t = threadIdx.x, l = t & 63, wv = t >> 6, g = l >> 4, c = l & 15;
  const int h = blockIdx.y, n0 = blockIdx.x * 64;
  f32x4 acc[4] = {};
  for (int k0 = 0; k0 < F_IN; k0 += 64){
    __syncthreads();
    #pragma unroll
    for (int p = 0; p < 4; ++p){
      int idx = t + p*256, row = idx >> 4, c4 = idx & 15;
      float4 v = *(const float4*)&x[(size_t)(n0+row)*F_IN + k0 + c4*4];
      *(uint2*)&xS[SWZ(row, c4*4)] = make_uint2(cvtpk(v.x, v.y), cvtpk(v.z, v.w));
    }
    #pragma unroll
    for (int p = 0; p < 2; ++p){
      int idx = t + p*256, o = idx >> 3, ch = idx & 7;
      *(s16x8*)&wS[SWZ(o, ch*8)] = *(const s16x8*)&WbT[(size_t)(h*HID + o)*F_IN + k0 + ch*8];
    }
    __syncthreads();
    #pragma unroll
    for (int ks = 0; ks < 2; ++ks){
      s16x8 av = *(const s16x8*)&xS[SWZ(wv*16 + c, ks*32 + g*8)];
      #pragma unroll
      for (int ct = 0; ct < 4; ++ct){
        s16x8 bv = *(const s16x8*)&wS[SWZ(ct*16 + c, ks*32 + g*8)];
        acc[ct] = __builtin_amdgcn_mfma_f32_16x16x32_bf16(av, bv, acc[ct], 0, 0, 0);
      }
    }
  }
  float asv[4], adv[4];
  #pragma unroll
  for (int ct = 0; ct < 4; ++ct){ asv[ct] = a_src[h*HID + ct*16 + c]; adv[ct] = a_dst[h*HID + ct*16 + c]; }
  #pragma unroll
  for (int r = 0; r < 4; ++r){
    float ps = acc[0][r]*asv[0] + acc[1][r]*asv[1] + acc[2][r]*asv[2] + acc[3][r]*asv[3];
    float pd = acc[0][r]*adv[0] + acc[1][r]*adv[1] + acc[2][r]*adv[2] + acc[3][r]*adv[3];
    #pragma unroll
    for (int off = 1; off < 16; off <<= 1){ ps += __shfl_xor(ps, off); pd += __shfl_xor(pd, off); }
    if (c == 0){ int n = n0 + wv*16 + g*4 + r; srcv[h*NN + n] = ps; dstv[h*NN + n] = pd; }
  }
  __syncthreads();
  #pragma unroll
  for (int ct = 0; ct < 4; ++ct)
    *(uint2*)&xS[SWZ(ct*16 + c, wv*16 + g*4)] = make_uint2(cvtpk(acc[ct][0], acc[ct][1]), cvtpk(acc[ct][2], acc[ct][3]));
  __syncthreads();
  #pragma unroll
  for (int p = 0; p < 2; ++p){
    int idx = t + p*256, o = idx >> 3, ch = idx & 7;
    *(s16x8*)&WhT[(size_t)(h*HID + o)*NN + n0 + ch*8] = *(const s16x8*)&xS[SWZ(o, ch*8)];
  }
}

// ---------------- per-4096-segment max reduce ----------------
__global__ __launch_bounds__(256) void maxred_k(const float* __restrict__ in, float* __restrict__ out){
  __shared__ float red[4];
  const float* p = in + (size_t)blockIdx.x*NN;
  float m = -3.0e38f;
  for (int i = threadIdx.x; i < NN; i += 256) m = fmaxf(m, p[i]);
  #pragma unroll
  for (int off = 32; off; off >>= 1) m = fmaxf(m, __shfl_xor(m, off));
  if ((threadIdx.x & 63) == 0) red[threadIdx.x >> 6] = m;
  __syncthreads();
  if (threadIdx.x == 0) out[blockIdx.x] = fmaxf(fmaxf(red[0], red[1]), fmaxf(red[2], red[3]));
}

// ---------------- MFMA masked-softmax aggregate v3 (Raf=2, register-safe) ----------------
// Block: 32 rows x one head. 4 waves = 4 j-parities, barrier-free j-loop.
// Each wave: 2 A-frags x NCT V-frags; V read DIRECTLY from global (L2-resident), each bv feeds 2 MFMAs.
// dS/bitS wave-private (parity dbuf). p_ij = bit * med3(A_i*B_j, C_i*D_j, 1). Row sums via ones-MFMA.
// Single-round LDS merge; wave 0 owns rows 0..15, wave 1 rows 16..31.
template<int NCT, int NJT, bool CHUNKED, bool DO_ELU>
__global__ __launch_bounds__(256) void agg_mfma_k(
    const unsigned* __restrict__ bmT, const unsigned short* __restrict__ VT,
    const float* __restrict__ srcv, const float* __restrict__ dstv,
    const float* __restrict__ maxp, void* __restrict__ outp)
{
  __shared__ float2 dS[4][2][64];          // [wave][parity][j]   (B_j, D_j)
  __shared__ unsigned bitS[4][2][2][32];   // [wave][parity][jword][row]
  __shared__ float mrg[2][3][16][NCT*16 + 4];
  const int t = threadIdx.x, l = t & 63, wv = t >> 6, g = l >> 4, c = l & 15;
  const int h   = CHUNKED ? 0 : blockIdx.y;
  const int jt0 = CHUNKED ? blockIdx.y * NJT : 0;
  const int i0 = blockIdx.x * 32;
  const float mx = maxp[CHUNKED ? 0 : h];
  f32x2 ac2[2];
  #pragma unroll
  for (int af = 0; af < 2; ++af){
    float sr = srcv[h*NN + i0 + af*16 + c];
    float tm = sr + mx;
    float mi2 = fmaxf(tm, 0.2f*tm) * LOG2E;
    ac2[af][0] = exp2f(fmaf(sr, LOG2E, -mi2));        // A_i
    ac2[af][1] = exp2f(fmaf(0.2f*sr, LOG2E, -mi2));   // C_i
  }
  const unsigned short* vb = VT + (CHUNKED ? (size_t)0 : (size_t)h*HID*NN);
  const float* dp = dstv + (size_t)h*NN;

  f32x4 acc[2][NCT] = {};
  f32x4 accs[2] = {};
  s16x8 ones;
  #pragma unroll
  for (int e = 0; e < 8; ++e) ones[e] = (short)0x3F80;

  // prefetch first tile scalars
  float dcur = dp[(jt0 + wv)*64 + l];
  unsigned bcur = bmT[(size_t)((jt0 + wv)*2 + (l>>5))*NN + i0 + (l & 31)];
  int pp = 0;
  for (int jt = jt0 + wv; jt < jt0 + NJT; jt += 4){
    // stage current tile's (B,D) + bits into wave-private LDS
    dS[wv][pp][l] = make_float2(exp2f(dcur*LOG2E), exp2f(0.2f*dcur*LOG2E));
    bitS[wv][pp][l>>5][l&31] = bcur;
    // prefetch next tile scalars
    if (jt + 4 < jt0 + NJT){
      dcur = dp[(jt+4)*64 + l];
      bcur = bmT[(size_t)((jt+4)*2 + (l>>5))*NN + i0 + (l & 31)];
    }
    asm volatile("s_waitcnt lgkmcnt(0)" ::: "memory");   // wave-internal LDS visibility
    #pragma unroll
    for (int ks = 0; ks < 2; ++ks){
      // V fragments straight from global (L2): 4 g-groups x 16B = perfect 64B lines
      s16x8 bv[NCT];
      #pragma unroll
      for (int ct = 0; ct < NCT; ++ct)
        bv[ct] = *(const s16x8*)&vb[(size_t)(ct*16 + c)*NN + jt*64 + ks*32 + g*8];
      f32x2 drv[8];
      #pragma unroll
      for (int e = 0; e < 8; ++e) drv[e] = *(const f32x2*)&dS[wv][pp][ks*32 + g*8 + e];
      #pragma unroll
      for (int af = 0; af < 2; ++af){
        unsigned wb = (bitS[wv][pp][ks][af*16 + c] >> (g*8)) & 0xffu;
        float q[8];
        #pragma unroll
        for (int e = 0; e < 8; ++e){
          f32x2 pr = pkmul(ac2[af], drv[e]);
          float m3 = __builtin_amdgcn_fmed3f(pr[0], pr[1], 1.0f);
          q[e] = (wb & (1u << e)) ? m3 : 0.f;
        }
        s16x8 afr;
        ((unsigned*)&afr)[0] = cvtpk(q[0], q[1]);
        ((unsigned*)&afr)[1] = cvtpk(q[2], q[3]);
        ((unsigned*)&afr)[2] = cvtpk(q[4], q[5]);
        ((unsigned*)&afr)[3] = cvtpk(q[6], q[7]);
        #pragma unroll
        for (int ct = 0; ct < NCT; ++ct)
          acc[af][ct] = __builtin_amdgcn_mfma_f32_16x16x32_bf16(afr, bv[ct], acc[af][ct], 0, 0, 0);
        accs[af] = __builtin_amdgcn_mfma_f32_16x16x32_bf16(afr, ones, accs[af], 0, 0, 0);
      }
    }
    pp ^= 1;
  }

  // single-round merge: waves != af write partials; owner wave af sums 3 sources
  __syncthreads();
  #pragma unroll
  for (int af = 0; af < 2; ++af){
    if (wv != af){
      int s = wv - (wv > af ? 1 : 0);
      #pragma unroll
      for (int ct = 0; ct < NCT; ++ct)
        #pragma unroll
        for (int r = 0; r < 4; ++r)
          mrg[af][s][g*4+r][ct*16+c] = acc[af][ct][r];
      if (c == 0){
        #pragma unroll
        for (int r = 0; r < 4; ++r) mrg[af][s][g*4+r][NCT*16] = accs[af][r];
      }
    }
  }
  __syncthreads();
  if (wv < 2){
    const int af = wv;
    #pragma unroll
    for (int ct = 0; ct < NCT; ++ct)
      #pragma unroll
      for (int r = 0; r < 4; ++r)
        acc[af][ct][r] += mrg[af][0][g*4+r][ct*16+c] + mrg[af][1][g*4+r][ct*16+c] + mrg[af][2][g*4+r][ct*16+c];
    #pragma unroll
    for (int r = 0; r < 4; ++r)
      accs[af][r] += mrg[af][0][g*4+r][NCT*16] + mrg[af][1][g*4+r][NCT*16] + mrg[af][2][g*4+r][NCT*16];

    if (!CHUNKED){
      unsigned short* ob = (unsigned short*)outp;
      #pragma unroll
      for (int r = 0; r < 4; ++r){
        float inv = 1.f / fmaxf(accs[af][r], 1e-30f);
        int row = i0 + af*16 + g*4 + r;
        #pragma unroll
        for (int ct = 0; ct < NCT; ++ct){
          float v = acc[af][ct][r] * inv;
          if (DO_ELU) v = v > 0.f ? v : __expf(v) - 1.f;
          ob[(size_t)row*(NHEAD*HID) + h*HID + ct*16 + c] = f2bf(v);
        }
      }
    } else {
      float* ob = (float*)outp + (size_t)blockIdx.y * NN * 64;
      #pragma unroll
      for (int r = 0; r < 4; ++r){
        int row = i0 + af*16 + g*4 + r;
        #pragma unroll
        for (int ct = 0; ct < NCT; ++ct)
          ob[(size_t)row*64 + ct*16 + c] = acc[af][ct][r];
        if (c == 0) ob[(size_t)row*64 + 48] = accs[af][r];
      }
    }
  }
}

// ---------------- gemm2: WhT2[c][n] bf16 = (h_bf16 @ W_out)^T ; s2/d2 fused ----------------
__global__ __launch_bounds__(256) void gemm2_k(const unsigned short* __restrict__ hb,
    const unsigned short* __restrict__ WoT, const float* __restrict__ aos, const float* __restrict__ aod,
    unsigned short* __restrict__ WhT2, float* __restrict__ s2, float* __restrict__ d2){
  __shared__ unsigned short aS[64*64];
  __shared__ unsigned short bS[48*64];
  const int t = threadIdx.x, l = t & 63, wv = t >> 6, g = l >> 4, c = l & 15;
  const int n0 = blockIdx.x * 64;
  f32x4 acc[3] = {};
  for (int k0 = 0; k0 < NHEAD*HID; k0 += 64){
    __syncthreads();
    #pragma unroll
    for (int p = 0; p < 2; ++p){
      int u = t + p*256, o = u >> 3, ch = u & 7;
      *(s16x8*)&aS[SWZ(o, ch*8)] = *(const s16x8*)&hb[(size_t)(n0+o)*(NHEAD*HID) + k0 + ch*8];
    }
    for (int u = t; u < 384; u += 256){
      int o = u >> 3, ch = u & 7;
      *(s16x8*)&bS[SWZ(o, ch*8)] = *(const s16x8*)&WoT[(size_t)o*(NHEAD*HID) + k0 + ch*8];
    }
    __syncthreads();
    #pragma unroll
    for (int ks = 0; ks < 2; ++ks){
      s16x8 av = *(const s16x8*)&aS[SWZ(wv*16 + c, ks*32 + g*8)];
      #pragma unroll
      for (int ct = 0; ct < 3; ++ct){
        s16x8 bv = *(const s16x8*)&bS[SWZ(ct*16 + c, ks*32 + g*8)];
        acc[ct] = __builtin_amdgcn_mfma_f32_16x16x32_bf16(av, bv, acc[ct], 0, 0, 0);
      }
    }
  }
  float asv[3], adv[3];
  #pragma unroll
  for (int ct = 0; ct < 3; ++ct){
    int col = ct*16 + c;
    asv[ct] = (col < NCLS) ? aos[col] : 0.f;
    adv[ct] = (col < NCLS) ? aod[col] : 0.f;
  }
  #pragma unroll
  for (int r = 0; r < 4; ++r){
    float ps = acc[0][r]*asv[0] + acc[1][r]*asv[1] + acc[2][r]*asv[2];
    float pd = acc[0][r]*adv[0] + acc[1][r]*adv[1] + acc[2][r]*adv[2];
    #pragma unroll
    for (int off = 1; off < 16; off <<= 1){ ps += __shfl_xor(ps, off); pd += __shfl_xor(pd, off); }
    if (c == 0){ int n = n0 + wv*16 + g*4 + r; s2[n] = ps; d2[n] = pd; }
  }
  __syncthreads();
  #pragma unroll
  for (int ct = 0; ct < 3; ++ct)
    *(uint2*)&bS[SWZ(ct*16 + c, wv*16 + g*4)] = make_uint2(cvtpk(acc[ct][0], acc[ct][1]), cvtpk(acc[ct][2], acc[ct][3]));
  __syncthreads();
  for (int u = t; u < 384; u += 256){
    int o = u >> 3, ch = u & 7;
    *(s16x8*)&WhT2[(size_t)o*NN + n0 + ch*8] = *(const s16x8*)&bS[SWZ(o, ch*8)];
  }
}

// ---------------- merge 8 chunks + elu + row log_softmax ----------------
__global__ __launch_bounds__(256) void final_k(const float* __restrict__ part, float* __restrict__ out){
  const int wid = (blockIdx.x*256 + threadIdx.x) >> 6;
  const int c = threadIdx.x & 63;
  float acc = 0.f, rs = 0.f;
  #pragma unroll
  for (int ch = 0; ch < 8; ++ch){
    const float* pb = part + ((size_t)ch*NN + wid)*64;
    if (c < 48) acc += pb[c];
    rs += pb[48];
  }
  float v = acc / fmaxf(rs, 1e-30f);
  float e = v > 0.f ? v : __expf(v) - 1.f;
  float ev = (c < NCLS) ? e : -3.0e38f;
  float m = ev;
  #pragma unroll
  for (int off = 32; off; off >>= 1) m = fmaxf(m, __shfl_xor(m, off));
  float ex = (c < NCLS) ? __expf(e - m) : 0.f;
  float s = ex;
  #pragma unroll
  for (int off = 32; off; off >>= 1) s += __shfl_xor(s, off);
  if (c < NCLS) out[(size_t)wid*NCLS + c] = e - m - __logf(s);
}

extern "C" void kernel_launch(void* const* d_in, const int* in_sizes, int n_in,
                              void* d_out, int out_size, void* d_ws, size_t ws_size,
                              hipStream_t stream){
  (void)in_sizes; (void)n_in; (void)out_size; (void)ws_size;
  const float* x     = (const float*)d_in[0];
  const int*   adj   = (const int*)  d_in[1];
  const float* W     = (const float*)d_in[2];
  const float* a_src = (const float*)d_in[3];
  const float* a_dst = (const float*)d_in[4];
  const float* W_out = (const float*)d_in[5];
  const float* aos   = (const float*)d_in[6];
  const float* aod   = (const float*)d_in[7];
  float* out = (float*)d_out;

  char* p = (char*)d_ws;
  unsigned* bmT        = (unsigned*)p;       p += (size_t)NN*128*4;            // 2 MB
  unsigned short* WbT  = (unsigned short*)p; p += (size_t)NHEAD*HID*F_IN*2;    // 1 MB
  unsigned short* WhT  = (unsigned short*)p; p += (size_t)NHEAD*HID*NN*2;      // 4 MB
  unsigned short* hbuf = (unsigned short*)p; p += (size_t)NN*NHEAD*HID*2;      // 4 MB
  unsigned short* WoT  = (unsigned short*)p; p += (size_t)48*NHEAD*HID*2;      // 48 KB
  unsigned short* WhT2 = (unsigned short*)p; p += (size_t)48*NN*2;             // 384 KB
  float* srcv = (float*)p; p += (size_t)NHEAD*NN*4;
  float* dstv = (float*)p; p += (size_t)NHEAD*NN*4;
  float* maxd = (float*)p; p += 256;
  float* s2   = (float*)p; p += (size_t)NN*4;
  float* d2   = (float*)p; p += (size_t)NN*4;
  float* m2   = (float*)p; p += 256;
  float* part = (float*)p; p += (size_t)8*NN*64*4;                             // 8 MB

  pack_adj_k<<<(NN*NN)/256, 256, 0, stream>>>(adj, bmT);
  cast_W_k<<<dim3(F_IN/64, NHEAD), 256, 0, stream>>>(W, WbT);
  cast_Wo_k<<<96, 256, 0, stream>>>(W_out, WoT);
  gemm1_k<<<dim3(NN/64, NHEAD), 256, 0, stream>>>(x, WbT, WhT, a_src, a_dst, srcv, dstv);
  maxred_k<<<NHEAD, 256, 0, stream>>>(dstv, maxd);
  agg_mfma_k<4, 64, false, true><<<dim3(NN/32, NHEAD), 256, 0, stream>>>(bmT, WhT, srcv, dstv, maxd, hbuf);
  gemm2_k<<<NN/64, 256, 0, stream>>>(hbuf, WoT, aos, aod, WhT2, s2, d2);
  maxred_k<<<1, 256, 0, stream>>>(d2, m2);
  agg_mfma_k<3, 8, true, false><<<dim3(NN/32, 8), 256, 0, stream>>>(bmT, WhT2, s2, d2, m2, part);
  final_k<<<NN/4, 256, 0, stream>>>(part, out);
}

// Round 11
// 190.937 us; speedup vs baseline: 1.1038x; 1.1038x over previous
//
#include <hip/hip_runtime.h>

#define NN 4096
#define F_IN 1024
#define NHEAD 8
#define HID 64
#define NCLS 40
#define LOG2E 1.44269504f

typedef float f32x4 __attribute__((ext_vector_type(4)));
typedef float f32x2 __attribute__((ext_vector_type(2)));
typedef short s16x8 __attribute__((ext_vector_type(8)));

// XOR-swizzled halfword index within a [R][64]-hw (128B-row) LDS tile:
// byte ^= (row&7)<<4  ->  halfword col ^= (row&7)<<3. 16B-chunk bijective per row.
#define SWZ(r,c) (((r)*64) + ((c) ^ (((r)&7)<<3)))

__device__ __forceinline__ unsigned short f2bf(float f){  // RNE float->bf16
  unsigned u = __float_as_uint(f);
  return (unsigned short)((u + 0x7fffu + ((u >> 16) & 1u)) >> 16);
}
__device__ __forceinline__ unsigned cvtpk(float lo, float hi){  // packed bf16 pair
  unsigned r; asm("v_cvt_pk_bf16_f32 %0, %1, %2" : "=v"(r) : "v"(lo), "v"(hi)); return r;
}
__device__ __forceinline__ f32x2 pkmul(f32x2 a, f32x2 b){  // packed fp32 dual mul
  f32x2 r; asm("v_pk_mul_f32 %0, %1, %2" : "=v"(r) : "v"(a), "v"(b)); return r;
}

// ---------------- pack adjacency -> word-transposed bitmask ----------------
__global__ __launch_bounds__(256) void pack_adj_k(const int* __restrict__ adj, unsigned* __restrict__ bmT){
  int gid = blockIdx.x*256 + threadIdx.x;
  int lane = threadIdx.x & 63;
  unsigned long long m = __ballot(adj[gid] > 0);
  int w = gid >> 5, i = w >> 7, jw = w & 127;
  if (lane == 0)       bmT[(size_t)jw*NN + i] = (unsigned)m;
  else if (lane == 32) bmT[(size_t)jw*NN + i] = (unsigned)(m >> 32);
}

// ---------------- WbT[h][o][k] = bf16(W[h][k][o]) ----------------
__global__ __launch_bounds__(256) void cast_W_k(const float* __restrict__ W, unsigned short* __restrict__ WbT){
  __shared__ float T[64][65];
  const int h = blockIdx.y, k0 = blockIdx.x*64, t = threadIdx.x;
  for (int idx = t; idx < 1024; idx += 256){
    int k = idx >> 4, c4 = idx & 15;
    *(float4*)&T[k][c4*4] = *(const float4*)&W[((size_t)h*F_IN + k0 + k)*HID + c4*4];
  }
  __syncthreads();
  for (int idx = t; idx < 512; idx += 256){
    int o = idx >> 3, ch = idx & 7;
    s16x8 v;
    #pragma unroll
    for (int e = 0; e < 8; ++e) v[e] = (short)f2bf(T[ch*8 + e][o]);
    *(s16x8*)&WbT[((size_t)h*HID + o)*F_IN + k0 + ch*8] = v;
  }
}

// ---------------- WoT[c][k] = bf16(W_out[k][c]), rows 40..47 zero ----------------
__global__ __launch_bounds__(256) void cast_Wo_k(const float* __restrict__ Wout, unsigned short* __restrict__ WoT){
  int idx = blockIdx.x*256 + threadIdx.x;   // 48*512
  int cc = idx >> 9, k = idx & 511;
  WoT[idx] = (cc < NCLS) ? f2bf(Wout[(size_t)k*NCLS + cc]) : (unsigned short)0;
}

// ---------------- gemm1: WhT[h][o][n] bf16 = (x@W)^T ; srcv/dstv fused epilogue ----------------
__global__ __launch_bounds__(256) void gemm1_k(const float* __restrict__ x,
    const unsigned short* __restrict__ WbT, unsigned short* __restrict__ WhT,
    const float* __restrict__ a_src, const float* __restrict__ a_dst,
    float* __restrict__ srcv, float* __restrict__ dstv){
  __shared__ unsigned short xS[64*64];
  __shared__ unsigned short wS[64*64];
  const int t = threadIdx.x, l = t & 63, wv = t >> 6, g = l >> 4, c = l & 15;
  const int h = blockIdx.y, n0 = blockIdx.x * 64;
  f32x4 acc[4] = {};
  for (int k0 = 0; k0 < F_IN; k0 += 64){
    __syncthreads();
    #pragma unroll
    for (int p = 0; p < 4; ++p){
      int idx = t + p*256, row = idx >> 4, c4 = idx & 15;
      float4 v = *(const float4*)&x[(size_t)(n0+row)*F_IN + k0 + c4*4];
      *(uint2*)&xS[SWZ(row, c4*4)] = make_uint2(cvtpk(v.x, v.y), cvtpk(v.z, v.w));
    }
    #pragma unroll
    for (int p = 0; p < 2; ++p){
      int idx = t + p*256, o = idx >> 3, ch = idx & 7;
      *(s16x8*)&wS[SWZ(o, ch*8)] = *(const s16x8*)&WbT[(size_t)(h*HID + o)*F_IN + k0 + ch*8];
    }
    __syncthreads();
    #pragma unroll
    for (int ks = 0; ks < 2; ++ks){
      s16x8 av = *(const s16x8*)&xS[SWZ(wv*16 + c, ks*32 + g*8)];
      #pragma unroll
      for (int ct = 0; ct < 4; ++ct){
        s16x8 bv = *(const s16x8*)&wS[SWZ(ct*16 + c, ks*32 + g*8)];
        acc[ct] = __builtin_amdgcn_mfma_f32_16x16x32_bf16(av, bv, acc[ct], 0, 0, 0);
      }
    }
  }
  float asv[4], adv[4];
  #pragma unroll
  for (int ct = 0; ct < 4; ++ct){ asv[ct] = a_src[h*HID + ct*16 + c]; adv[ct] = a_dst[h*HID + ct*16 + c]; }
  #pragma unroll
  for (int r = 0; r < 4; ++r){
    float ps = acc[0][r]*asv[0] + acc[1][r]*asv[1] + acc[2][r]*asv[2] + acc[3][r]*asv[3];
    float pd = acc[0][r]*adv[0] + acc[1][r]*adv[1] + acc[2][r]*adv[2] + acc[3][r]*adv[3];
    #pragma unroll
    for (int off = 1; off < 16; off <<= 1){ ps += __shfl_xor(ps, off); pd += __shfl_xor(pd, off); }
    if (c == 0){ int n = n0 + wv*16 + g*4 + r; srcv[h*NN + n] = ps; dstv[h*NN + n] = pd; }
  }
  __syncthreads();
  #pragma unroll
  for (int ct = 0; ct < 4; ++ct)
    *(uint2*)&xS[SWZ(ct*16 + c, wv*16 + g*4)] = make_uint2(cvtpk(acc[ct][0], acc[ct][1]), cvtpk(acc[ct][2], acc[ct][3]));
  __syncthreads();
  #pragma unroll
  for (int p = 0; p < 2; ++p){
    int idx = t + p*256, o = idx >> 3, ch = idx & 7;
    *(s16x8*)&WhT[(size_t)(h*HID + o)*NN + n0 + ch*8] = *(const s16x8*)&xS[SWZ(o, ch*8)];
  }
}

// ---------------- per-4096-segment max reduce ----------------
__global__ __launch_bounds__(256) void maxred_k(const float* __restrict__ in, float* __restrict__ out){
  __shared__ float red[4];
  const float* p = in + (size_t)blockIdx.x*NN;
  float m = -3.0e38f;
  for (int i = threadIdx.x; i < NN; i += 256) m = fmaxf(m, p[i]);
  #pragma unroll
  for (int off = 32; off; off >>= 1) m = fmaxf(m, __shfl_xor(m, off));
  if ((threadIdx.x & 63) == 0) red[threadIdx.x >> 6] = m;
  __syncthreads();
  if (threadIdx.x == 0) out[blockIdx.x] = fmaxf(fmaxf(red[0], red[1]), fmaxf(red[2], red[3]));
}

// ---------------- MFMA masked-softmax aggregate v4 (wave-private LDS staging) ----------------
// Block: 32 rows x one head. 4 waves = 4 j-parities, barrier-free j-loop.
// Per tile: wave loads 8KB V tile (dense b128, coalesced) -> private vS quadrant -> reads 8
// fragments back, each feeding 2 MFMAs (Raf=2). dS/bitS wave-private ping-pong (scalar prefetch).
// p_ij = bit * med3(A_i*B_j, C_i*D_j, 1). Row sums via ones-MFMA. Single-round merge aliases vS.
template<int NCT, int NJT, bool CHUNKED, bool DO_ELU>
__global__ __launch_bounds__(256) void agg_mfma_k(
    const unsigned* __restrict__ bmT, const unsigned short* __restrict__ VT,
    const float* __restrict__ srcv, const float* __restrict__ dstv,
    const float* __restrict__ maxp, void* __restrict__ outp)
{
  constexpr int NV = NCT*2;                 // b128 loads per lane per tile
  __shared__ unsigned short vS[4][NCT*16*64];  // wave-private V tile (single buffer)
  __shared__ float2 dS[4][2][64];              // [wave][parity][j]   (B_j, D_j)
  __shared__ unsigned bitS[4][2][2][32];       // [wave][parity][jword][row]
  const int t = threadIdx.x, l = t & 63, wv = t >> 6, g = l >> 4, c = l & 15;
  const int h   = CHUNKED ? 0 : blockIdx.y;
  const int jt0 = CHUNKED ? blockIdx.y * NJT : 0;
  const int i0 = blockIdx.x * 32;
  const float mx = maxp[CHUNKED ? 0 : h];
  f32x2 ac2[2];
  #pragma unroll
  for (int af = 0; af < 2; ++af){
    float sr = srcv[h*NN + i0 + af*16 + c];
    float tm = sr + mx;
    float mi2 = fmaxf(tm, 0.2f*tm) * LOG2E;
    ac2[af][0] = exp2f(fmaf(sr, LOG2E, -mi2));        // A_i
    ac2[af][1] = exp2f(fmaf(0.2f*sr, LOG2E, -mi2));   // C_i
  }
  const unsigned short* vb = VT + (CHUNKED ? (size_t)0 : (size_t)h*HID*NN);
  const float* dp = dstv + (size_t)h*NN;

  f32x4 acc[2][NCT] = {};
  f32x4 accs[2] = {};
  s16x8 ones;
  #pragma unroll
  for (int e = 0; e < 8; ++e) ones[e] = (short)0x3F80;

  const int ro = l >> 3, c8 = l & 7;        // staging coords: 8 rows x 8 col-chunks
  // prefetch first tile scalars
  float dcur = dp[(jt0 + wv)*64 + l];
  unsigned bcur = bmT[(size_t)((jt0 + wv)*2 + (l>>5))*NN + i0 + (l & 31)];
  int pp = 0;
  for (int jt = jt0 + wv; jt < jt0 + NJT; jt += 4){
    // dense-stage this wave's V tile into its private vS quadrant
    s16x8 vreg[NV];
    #pragma unroll
    for (int p = 0; p < NV; ++p)
      vreg[p] = *(const s16x8*)&vb[(size_t)(p*8 + ro)*NN + jt*64 + c8*8];
    #pragma unroll
    for (int p = 0; p < NV; ++p)
      *(s16x8*)&vS[wv][SWZ(p*8 + ro, c8*8)] = vreg[p];
    // stage (B,D) + bits
    dS[wv][pp][l] = make_float2(exp2f(dcur*LOG2E), exp2f(0.2f*dcur*LOG2E));
    bitS[wv][pp][l>>5][l&31] = bcur;
    // prefetch next tile scalars
    if (jt + 4 < jt0 + NJT){
      dcur = dp[(jt+4)*64 + l];
      bcur = bmT[(size_t)((jt+4)*2 + (l>>5))*NN + i0 + (l & 31)];
    }
    asm volatile("s_waitcnt lgkmcnt(0)" ::: "memory");   // wave-internal LDS visibility
    #pragma unroll
    for (int ks = 0; ks < 2; ++ks){
      s16x8 bv[NCT];
      #pragma unroll
      for (int ct = 0; ct < NCT; ++ct)
        bv[ct] = *(const s16x8*)&vS[wv][SWZ(ct*16 + c, ks*32 + g*8)];
      f32x2 drv[8];
      #pragma unroll
      for (int e = 0; e < 8; ++e) drv[e] = *(const f32x2*)&dS[wv][pp][ks*32 + g*8 + e];
      #pragma unroll
      for (int af = 0; af < 2; ++af){
        unsigned wb = (bitS[wv][pp][ks][af*16 + c] >> (g*8)) & 0xffu;
        float q[8];
        #pragma unroll
        for (int e = 0; e < 8; ++e){
          f32x2 pr = pkmul(ac2[af], drv[e]);
          float m3 = __builtin_amdgcn_fmed3f(pr[0], pr[1], 1.0f);
          q[e] = (wb & (1u << e)) ? m3 : 0.f;
        }
        s16x8 afr;
        ((unsigned*)&afr)[0] = cvtpk(q[0], q[1]);
        ((unsigned*)&afr)[1] = cvtpk(q[2], q[3]);
        ((unsigned*)&afr)[2] = cvtpk(q[4], q[5]);
        ((unsigned*)&afr)[3] = cvtpk(q[6], q[7]);
        #pragma unroll
        for (int ct = 0; ct < NCT; ++ct)
          acc[af][ct] = __builtin_amdgcn_mfma_f32_16x16x32_bf16(afr, bv[ct], acc[af][ct], 0, 0, 0);
        accs[af] = __builtin_amdgcn_mfma_f32_16x16x32_bf16(afr, ones, accs[af], 0, 0, 0);
      }
    }
    pp ^= 1;
  }

  // single-round merge (buffer aliases dead vS): waves != af write partials; owner af sums 3
  __syncthreads();
  constexpr int MW = NCT*16 + 4;
  float* mrgf = (float*)&vS[0][0];
  #pragma unroll
  for (int af = 0; af < 2; ++af){
    if (wv != af){
      int s = wv - (wv > af ? 1 : 0);
      #pragma unroll
      for (int ct = 0; ct < NCT; ++ct)
        #pragma unroll
        for (int r = 0; r < 4; ++r)
          mrgf[((af*3 + s)*16 + g*4 + r)*MW + ct*16 + c] = acc[af][ct][r];
      if (c == 0){
        #pragma unroll
        for (int r = 0; r < 4; ++r) mrgf[((af*3 + s)*16 + g*4 + r)*MW + NCT*16] = accs[af][r];
      }
    }
  }
  __syncthreads();
  if (wv < 2){
    const int af = wv;
    #pragma unroll
    for (int ct = 0; ct < NCT; ++ct)
      #pragma unroll
      for (int r = 0; r < 4; ++r)
        acc[af][ct][r] += mrgf[((af*3+0)*16 + g*4+r)*MW + ct*16+c]
                        + mrgf[((af*3+1)*16 + g*4+r)*MW + ct*16+c]
                        + mrgf[((af*3+2)*16 + g*4+r)*MW + ct*16+c];
    #pragma unroll
    for (int r = 0; r < 4; ++r)
      accs[af][r] += mrgf[((af*3+0)*16 + g*4+r)*MW + NCT*16]
                   + mrgf[((af*3+1)*16 + g*4+r)*MW + NCT*16]
                   + mrgf[((af*3+2)*16 + g*4+r)*MW + NCT*16];

    if (!CHUNKED){
      unsigned short* ob = (unsigned short*)outp;
      #pragma unroll
      for (int r = 0; r < 4; ++r){
        float inv = 1.f / fmaxf(accs[af][r], 1e-30f);
        int row = i0 + af*16 + g*4 + r;
        #pragma unroll
        for (int ct = 0; ct < NCT; ++ct){
          float v = acc[af][ct][r] * inv;
          if (DO_ELU) v = v > 0.f ? v : __expf(v) - 1.f;
          ob[(size_t)row*(NHEAD*HID) + h*HID + ct*16 + c] = f2bf(v);
        }
      }
    } else {
      float* ob = (float*)outp + (size_t)blockIdx.y * NN * 64;
      #pragma unroll
      for (int r = 0; r < 4; ++r){
        int row = i0 + af*16 + g*4 + r;
        #pragma unroll
        for (int ct = 0; ct < NCT; ++ct)
          ob[(size_t)row*64 + ct*16 + c] = acc[af][ct][r];
        if (c == 0) ob[(size_t)row*64 + 48] = accs[af][r];
      }
    }
  }
}

// ---------------- gemm2: WhT2[c][n] bf16 = (h_bf16 @ W_out)^T ; s2/d2 fused ----------------
__global__ __launch_bounds__(256) void gemm2_k(const unsigned short* __restrict__ hb,
    const unsigned short* __restrict__ WoT, const float* __restrict__ aos, const float* __restrict__ aod,
    unsigned short* __restrict__ WhT2, float* __restrict__ s2, float* __restrict__ d2){
  __shared__ unsigned short aS[64*64];
  __shared__ unsigned short bS[48*64];
  const int t = threadIdx.x, l = t & 63, wv = t >> 6, g = l >> 4, c = l & 15;
  const int n0 = blockIdx.x * 64;
  f32x4 acc[3] = {};
  for (int k0 = 0; k0 < NHEAD*HID; k0 += 64){
    __syncthreads();
    #pragma unroll
    for (int p = 0; p < 2; ++p){
      int u = t + p*256, o = u >> 3, ch = u & 7;
      *(s16x8*)&aS[SWZ(o, ch*8)] = *(const s16x8*)&hb[(size_t)(n0+o)*(NHEAD*HID) + k0 + ch*8];
    }
    for (int u = t; u < 384; u += 256){
      int o = u >> 3, ch = u & 7;
      *(s16x8*)&bS[SWZ(o, ch*8)] = *(const s16x8*)&WoT[(size_t)o*(NHEAD*HID) + k0 + ch*8];
    }
    __syncthreads();
    #pragma unroll
    for (int ks = 0; ks < 2; ++ks){
      s16x8 av = *(const s16x8*)&aS[SWZ(wv*16 + c, ks*32 + g*8)];
      #pragma unroll
      for (int ct = 0; ct < 3; ++ct){
        s16x8 bv = *(const s16x8*)&bS[SWZ(ct*16 + c, ks*32 + g*8)];
        acc[ct] = __builtin_amdgcn_mfma_f32_16x16x32_bf16(av, bv, acc[ct], 0, 0, 0);
      }
    }
  }
  float asv[3], adv[3];
  #pragma unroll
  for (int ct = 0; ct < 3; ++ct){
    int col = ct*16 + c;
    asv[ct] = (col < NCLS) ? aos[col] : 0.f;
    adv[ct] = (col < NCLS) ? aod[col] : 0.f;
  }
  #pragma unroll
  for (int r = 0; r < 4; ++r){
    float ps = acc[0][r]*asv[0] + acc[1][r]*asv[1] + acc[2][r]*asv[2];
    float pd = acc[0][r]*adv[0] + acc[1][r]*adv[1] + acc[2][r]*adv[2];
    #pragma unroll
    for (int off = 1; off < 16; off <<= 1){ ps += __shfl_xor(ps, off); pd += __shfl_xor(pd, off); }
    if (c == 0){ int n = n0 + wv*16 + g*4 + r; s2[n] = ps; d2[n] = pd; }
  }
  __syncthreads();
  #pragma unroll
  for (int ct = 0; ct < 3; ++ct)
    *(uint2*)&bS[SWZ(ct*16 + c, wv*16 + g*4)] = make_uint2(cvtpk(acc[ct][0], acc[ct][1]), cvtpk(acc[ct][2], acc[ct][3]));
  __syncthreads();
  for (int u = t; u < 384; u += 256){
    int o = u >> 3, ch = u & 7;
    *(s16x8*)&WhT2[(size_t)o*NN + n0 + ch*8] = *(const s16x8*)&bS[SWZ(o, ch*8)];
  }
}

// ---------------- merge 8 chunks + elu + row log_softmax ----------------
__global__ __launch_bounds__(256) void final_k(const float* __restrict__ part, float* __restrict__ out){
  const int wid = (blockIdx.x*256 + threadIdx.x) >> 6;
  const int c = threadIdx.x & 63;
  float acc = 0.f, rs = 0.f;
  #pragma unroll
  for (int ch = 0; ch < 8; ++ch){
    const float* pb = part + ((size_t)ch*NN + wid)*64;
    if (c < 48) acc += pb[c];
    rs += pb[48];
  }
  float v = acc / fmaxf(rs, 1e-30f);
  float e = v > 0.f ? v : __expf(v) - 1.f;
  float ev = (c < NCLS) ? e : -3.0e38f;
  float m = ev;
  #pragma unroll
  for (int off = 32; off; off >>= 1) m = fmaxf(m, __shfl_xor(m, off));
  float ex = (c < NCLS) ? __expf(e - m) : 0.f;
  float s = ex;
  #pragma unroll
  for (int off = 32; off; off >>= 1) s += __shfl_xor(s, off);
  if (c < NCLS) out[(size_t)wid*NCLS + c] = e - m - __logf(s);
}

extern "C" void kernel_launch(void* const* d_in, const int* in_sizes, int n_in,
                              void* d_out, int out_size, void* d_ws, size_t ws_size,
                              hipStream_t stream){
  (void)in_sizes; (void)n_in; (void)out_size; (void)ws_size;
  const float* x     = (const float*)d_in[0];
  const int*   adj   = (const int*)  d_in[1];
  const float* W     = (const float*)d_in[2];
  const float* a_src = (const float*)d_in[3];
  const float* a_dst = (const float*)d_in[4];
  const float* W_out = (const float*)d_in[5];
  const float* aos   = (const float*)d_in[6];
  const float* aod   = (const float*)d_in[7];
  float* out = (float*)d_out;

  char* p = (char*)d_ws;
  unsigned* bmT        = (unsigned*)p;       p += (size_t)NN*128*4;            // 2 MB
  unsigned short* WbT  = (unsigned short*)p; p += (size_t)NHEAD*HID*F_IN*2;    // 1 MB
  unsigned short* WhT  = (unsigned short*)p; p += (size_t)NHEAD*HID*NN*2;      // 4 MB
  unsigned short* hbuf = (unsigned short*)p; p += (size_t)NN*NHEAD*HID*2;      // 4 MB
  unsigned short* WoT  = (unsigned short*)p; p += (size_t)48*NHEAD*HID*2;      // 48 KB
  unsigned short* WhT2 = (unsigned short*)p; p += (size_t)48*NN*2;             // 384 KB
  float* srcv = (float*)p; p += (size_t)NHEAD*NN*4;
  float* dstv = (float*)p; p += (size_t)NHEAD*NN*4;
  float* maxd = (float*)p; p += 256;
  float* s2   = (float*)p; p += (size_t)NN*4;
  float* d2   = (float*)p; p += (size_t)NN*4;
  float* m2   = (float*)p; p += 256;
  float* part = (float*)p; p += (size_t)8*NN*64*4;                             // 8 MB

  pack_adj_k<<<(NN*NN)/256, 256, 0, stream>>>(adj, bmT);
  cast_W_k<<<dim3(F_IN/64, NHEAD), 256, 0, stream>>>(W, WbT);
  cast_Wo_k<<<96, 256, 0, stream>>>(W_out, WoT);
  gemm1_k<<<dim3(NN/64, NHEAD), 256, 0, stream>>>(x, WbT, WhT, a_src, a_dst, srcv, dstv);
  maxred_k<<<NHEAD, 256, 0, stream>>>(dstv, maxd);
  agg_mfma_k<4, 64, false, true><<<dim3(NN/32, NHEAD), 256, 0, stream>>>(bmT, WhT, srcv, dstv, maxd, hbuf);
  gemm2_k<<<NN/64, 256, 0, stream>>>(hbuf, WoT, aos, aod, WhT2, s2, d2);
  maxred_k<<<1, 256, 0, stream>>>(d2, m2);
  agg_mfma_k<3, 8, true, false><<<dim3(NN/32, 8), 256, 0, stream>>>(bmT, WhT2, s2, d2, m2, part);
  final_k<<<NN/4, 256, 0, stream>>>(part, out);
}

// Round 12
// 163.339 us; speedup vs baseline: 1.2903x; 1.1690x over previous
//
#include <hip/hip_runtime.h>

#define NN 4096
#define F_IN 1024
#define NHEAD 8
#define HID 64
#define NCLS 40
#define LOG2E 1.44269504f

typedef float f32x4 __attribute__((ext_vector_type(4)));
typedef float f32x2 __attribute__((ext_vector_type(2)));
typedef short s16x8 __attribute__((ext_vector_type(8)));

// XOR-swizzled halfword index within a [R][64]-hw (128B-row) LDS tile:
// byte ^= (row&7)<<4  ->  halfword col ^= (row&7)<<3. 16B-chunk bijective per row.
#define SWZ(r,c) (((r)*64) + ((c) ^ (((r)&7)<<3)))

__device__ __forceinline__ unsigned short f2bf(float f){  // RNE float->bf16
  unsigned u = __float_as_uint(f);
  return (unsigned short)((u + 0x7fffu + ((u >> 16) & 1u)) >> 16);
}
__device__ __forceinline__ unsigned cvtpk(float lo, float hi){  // packed bf16 pair
  unsigned r; asm("v_cvt_pk_bf16_f32 %0, %1, %2" : "=v"(r) : "v"(lo), "v"(hi)); return r;
}
__device__ __forceinline__ f32x2 pkmul(f32x2 a, f32x2 b){  // packed fp32 dual mul
  f32x2 r; asm("v_pk_mul_f32 %0, %1, %2" : "=v"(r) : "v"(a), "v"(b)); return r;
}

// ---------------- pack adjacency -> word-transposed bitmask ----------------
__global__ __launch_bounds__(256) void pack_adj_k(const int* __restrict__ adj, unsigned* __restrict__ bmT){
  int gid = blockIdx.x*256 + threadIdx.x;
  int lane = threadIdx.x & 63;
  unsigned long long m = __ballot(adj[gid] > 0);
  int w = gid >> 5, i = w >> 7, jw = w & 127;
  if (lane == 0)       bmT[(size_t)jw*NN + i] = (unsigned)m;
  else if (lane == 32) bmT[(size_t)jw*NN + i] = (unsigned)(m >> 32);
}

// ---------------- WbT[h][o][k] = bf16(W[h][k][o]) ----------------
__global__ __launch_bounds__(256) void cast_W_k(const float* __restrict__ W, unsigned short* __restrict__ WbT){
  __shared__ float T[64][65];
  const int h = blockIdx.y, k0 = blockIdx.x*64, t = threadIdx.x;
  for (int idx = t; idx < 1024; idx += 256){
    int k = idx >> 4, c4 = idx & 15;
    *(float4*)&T[k][c4*4] = *(const float4*)&W[((size_t)h*F_IN + k0 + k)*HID + c4*4];
  }
  __syncthreads();
  for (int idx = t; idx < 512; idx += 256){
    int o = idx >> 3, ch = idx & 7;
    s16x8 v;
    #pragma unroll
    for (int e = 0; e < 8; ++e) v[e] = (short)f2bf(T[ch*8 + e][o]);
    *(s16x8*)&WbT[((size_t)h*HID + o)*F_IN + k0 + ch*8] = v;
  }
}

// ---------------- WoT[c][k] = bf16(W_out[k][c]), rows 40..47 zero ----------------
__global__ __launch_bounds__(256) void cast_Wo_k(const float* __restrict__ Wout, unsigned short* __restrict__ WoT){
  int idx = blockIdx.x*256 + threadIdx.x;   // 48*512
  int cc = idx >> 9, k = idx & 511;
  WoT[idx] = (cc < NCLS) ? f2bf(Wout[(size_t)k*NCLS + cc]) : (unsigned short)0;
}

// ---------------- gemm1: WhT[h][o][n] bf16 = (x@W)^T ; srcv/dstv/bdv fused epilogue ----------------
__global__ __launch_bounds__(256) void gemm1_k(const float* __restrict__ x,
    const unsigned short* __restrict__ WbT, unsigned short* __restrict__ WhT,
    const float* __restrict__ a_src, const float* __restrict__ a_dst,
    float* __restrict__ srcv, float* __restrict__ dstv, float2* __restrict__ bdv){
  __shared__ unsigned short xS[64*64];
  __shared__ unsigned short wS[64*64];
  const int t = threadIdx.x, l = t & 63, wv = t >> 6, g = l >> 4, c = l & 15;
  const int h = blockIdx.y, n0 = blockIdx.x * 64;
  f32x4 acc[4] = {};
  for (int k0 = 0; k0 < F_IN; k0 += 64){
    __syncthreads();
    #pragma unroll
    for (int p = 0; p < 4; ++p){
      int idx = t + p*256, row = idx >> 4, c4 = idx & 15;
      float4 v = *(const float4*)&x[(size_t)(n0+row)*F_IN + k0 + c4*4];
      *(uint2*)&xS[SWZ(row, c4*4)] = make_uint2(cvtpk(v.x, v.y), cvtpk(v.z, v.w));
    }
    #pragma unroll
    for (int p = 0; p < 2; ++p){
      int idx = t + p*256, o = idx >> 3, ch = idx & 7;
      *(s16x8*)&wS[SWZ(o, ch*8)] = *(const s16x8*)&WbT[(size_t)(h*HID + o)*F_IN + k0 + ch*8];
    }
    __syncthreads();
    #pragma unroll
    for (int ks = 0; ks < 2; ++ks){
      s16x8 av = *(const s16x8*)&xS[SWZ(wv*16 + c, ks*32 + g*8)];
      #pragma unroll
      for (int ct = 0; ct < 4; ++ct){
        s16x8 bv = *(const s16x8*)&wS[SWZ(ct*16 + c, ks*32 + g*8)];
        acc[ct] = __builtin_amdgcn_mfma_f32_16x16x32_bf16(av, bv, acc[ct], 0, 0, 0);
      }
    }
  }
  float asv[4], adv[4];
  #pragma unroll
  for (int ct = 0; ct < 4; ++ct){ asv[ct] = a_src[h*HID + ct*16 + c]; adv[ct] = a_dst[h*HID + ct*16 + c]; }
  #pragma unroll
  for (int r = 0; r < 4; ++r){
    float ps = acc[0][r]*asv[0] + acc[1][r]*asv[1] + acc[2][r]*asv[2] + acc[3][r]*asv[3];
    float pd = acc[0][r]*adv[0] + acc[1][r]*adv[1] + acc[2][r]*adv[2] + acc[3][r]*adv[3];
    #pragma unroll
    for (int off = 1; off < 16; off <<= 1){ ps += __shfl_xor(ps, off); pd += __shfl_xor(pd, off); }
    if (c == 0){
      int n = n0 + wv*16 + g*4 + r;
      srcv[h*NN + n] = ps; dstv[h*NN + n] = pd;
      bdv[h*NN + n] = make_float2(exp2f(pd*LOG2E), exp2f(0.2f*pd*LOG2E));
    }
  }
  __syncthreads();
  #pragma unroll
  for (int ct = 0; ct < 4; ++ct)
    *(uint2*)&xS[SWZ(ct*16 + c, wv*16 + g*4)] = make_uint2(cvtpk(acc[ct][0], acc[ct][1]), cvtpk(acc[ct][2], acc[ct][3]));
  __syncthreads();
  #pragma unroll
  for (int p = 0; p < 2; ++p){
    int idx = t + p*256, o = idx >> 3, ch = idx & 7;
    *(s16x8*)&WhT[(size_t)(h*HID + o)*NN + n0 + ch*8] = *(const s16x8*)&xS[SWZ(o, ch*8)];
  }
}

// ---------------- per-4096-segment max reduce ----------------
__global__ __launch_bounds__(256) void maxred_k(const float* __restrict__ in, float* __restrict__ out){
  __shared__ float red[4];
  const float* p = in + (size_t)blockIdx.x*NN;
  float m = -3.0e38f;
  for (int i = threadIdx.x; i < NN; i += 256) m = fmaxf(m, p[i]);
  #pragma unroll
  for (int off = 32; off; off >>= 1) m = fmaxf(m, __shfl_xor(m, off));
  if ((threadIdx.x & 63) == 0) red[threadIdx.x >> 6] = m;
  __syncthreads();
  if (threadIdx.x == 0) out[blockIdx.x] = fmaxf(fmaxf(red[0], red[1]), fmaxf(red[2], red[3]));
}

// ---------------- MFMA masked-softmax aggregate (r8 skeleton; (B,D)/bits direct from L2) ----------------
// Block: 32 rows x one head; 4 waves = j-parity tl(2) x row-half rH(2).
// Per iteration: loadRegs(next) -> computeBuf(cur) -> writeLDS(cur^1) -> barrier (ping-pong vS only).
// p_ij = bit * med3(A_i*B_j, C_i*D_j, 1); (B,D) = bdv (precomputed in gemm epilogues), read per-lane
// from L2 (64B contiguous per ks); bits one b32/ks from bmT. Row sums via ones-MFMA.
template<int NCT, int NJT, bool CHUNKED, bool DO_ELU>
__global__ __launch_bounds__(256) void agg_mfma_k(
    const unsigned* __restrict__ bmT, const unsigned short* __restrict__ VT,
    const float* __restrict__ srcv, const float2* __restrict__ bdv,
    const float* __restrict__ maxp, void* __restrict__ outp)
{
  __shared__ unsigned short vS[2][2][NCT*16*64];
  const int t = threadIdx.x, l = t & 63, wv = t >> 6, g = l >> 4, c = l & 15;
  const int h   = CHUNKED ? 0 : blockIdx.y;
  const int jt0 = CHUNKED ? blockIdx.y * NJT : 0;
  const int i0 = blockIdx.x * 32;
  const int tl = wv >> 1, rH = wv & 1;
  const int lr = rH*16 + c;
  const float sr = srcv[h*NN + i0 + lr];
  const float mx = maxp[CHUNKED ? 0 : h];
  const float tm = sr + mx;
  const float mi2 = fmaxf(tm, 0.2f*tm) * LOG2E;
  f32x2 ac2;
  ac2[0] = exp2f(fmaf(sr, LOG2E, -mi2));        // A_i
  ac2[1] = exp2f(fmaf(0.2f*sr, LOG2E, -mi2));   // C_i
  const unsigned short* vb = VT + (CHUNKED ? (size_t)0 : (size_t)h*HID*NN);
  const float2* bp = bdv + (CHUNKED ? (size_t)0 : (size_t)h*NN);

  f32x4 acc[NCT] = {};
  f32x4 accs = {};
  s16x8 ones;
  #pragma unroll
  for (int e = 0; e < 8; ++e) ones[e] = (short)0x3F80;

  s16x8 vreg[NCT];
  auto loadRegs = [&](int jt){
    #pragma unroll
    for (int p = 0; p < NCT; ++p){
      int u = t + p*256;
      int tt = u / (NCT*128), rem = u % (NCT*128);
      int o = rem >> 3, chk = rem & 7;
      vreg[p] = *(const s16x8*)&vb[(size_t)o*NN + (jt+tt)*64 + chk*8];
    }
  };
  auto writeLDS = [&](int b){
    #pragma unroll
    for (int p = 0; p < NCT; ++p){
      int u = t + p*256;
      int tt = u / (NCT*128), rem = u % (NCT*128);
      int o = rem >> 3, chk = rem & 7;
      *(s16x8*)&vS[b][tt][SWZ(o, chk*8)] = vreg[p];
    }
  };
  auto computeBuf = [&](int b, int jtile){
    unsigned wbit[2];
    wbit[0] = bmT[(size_t)(jtile*2 + 0)*NN + i0 + lr];
    wbit[1] = bmT[(size_t)(jtile*2 + 1)*NN + i0 + lr];
    #pragma unroll
    for (int ks = 0; ks < 2; ++ks){
      f32x2 drv[8];
      #pragma unroll
      for (int e = 0; e < 8; ++e) drv[e] = *(const f32x2*)&bp[jtile*64 + ks*32 + g*8 + e];
      s16x8 bv[NCT];
      #pragma unroll
      for (int ct = 0; ct < NCT; ++ct)
        bv[ct] = *(const s16x8*)&vS[b][tl][SWZ(ct*16 + c, ks*32 + g*8)];
      unsigned wb = (wbit[ks] >> (g*8)) & 0xffu;
      float q[8];
      #pragma unroll
      for (int e = 0; e < 8; ++e){
        f32x2 pr = pkmul(ac2, drv[e]);
        float m3 = __builtin_amdgcn_fmed3f(pr[0], pr[1], 1.0f);
        q[e] = (wb & (1u << e)) ? m3 : 0.f;
      }
      s16x8 afr;
      ((unsigned*)&afr)[0] = cvtpk(q[0], q[1]);
      ((unsigned*)&afr)[1] = cvtpk(q[2], q[3]);
      ((unsigned*)&afr)[2] = cvtpk(q[4], q[5]);
      ((unsigned*)&afr)[3] = cvtpk(q[6], q[7]);
      #pragma unroll
      for (int ct = 0; ct < NCT; ++ct)
        acc[ct] = __builtin_amdgcn_mfma_f32_16x16x32_bf16(afr, bv[ct], acc[ct], 0, 0, 0);
      accs = __builtin_amdgcn_mfma_f32_16x16x32_bf16(afr, ones, accs, 0, 0, 0);
    }
  };

  // prologue: stage first pair into buf 0
  loadRegs(jt0);
  writeLDS(0);
  __syncthreads();
  int cur = 0;
  for (int jj = 0; jj < NJT; jj += 2){
    const bool more = (jj + 2 < NJT);
    if (more) loadRegs(jt0 + jj + 2);   // issue next-pair globals early
    computeBuf(cur, jt0 + jj + tl);     // consume own-parity tile
    if (more) writeLDS(cur ^ 1);        // write-late into other buffer
    __syncthreads();                    // single barrier per iteration
    cur ^= 1;
  }

  // merge j-parity wave pairs via LDS (aliases vS)
  float* mrg = (float*)&vS[0][0][0];
  constexpr int S = (NCT + 1) * 4;
  if (tl == 1){
    int base = (rH*64 + l) * S;
    #pragma unroll
    for (int ct = 0; ct < NCT; ++ct)
      #pragma unroll
      for (int r = 0; r < 4; ++r) mrg[base + ct*4 + r] = acc[ct][r];
    #pragma unroll
    for (int r = 0; r < 4; ++r) mrg[base + NCT*4 + r] = accs[r];
  }
  __syncthreads();
  if (tl == 0){
    int base = (rH*64 + l) * S;
    #pragma unroll
    for (int ct = 0; ct < NCT; ++ct)
      #pragma unroll
      for (int r = 0; r < 4; ++r) acc[ct][r] += mrg[base + ct*4 + r];
    #pragma unroll
    for (int r = 0; r < 4; ++r) accs[r] += mrg[base + NCT*4 + r];
    if (!CHUNKED){
      unsigned short* ob = (unsigned short*)outp;
      #pragma unroll
      for (int r = 0; r < 4; ++r){
        float inv = 1.f / fmaxf(accs[r], 1e-30f);
        int row = i0 + rH*16 + g*4 + r;
        #pragma unroll
        for (int ct = 0; ct < NCT; ++ct){
          float v = acc[ct][r] * inv;
          if (DO_ELU) v = v > 0.f ? v : __expf(v) - 1.f;
          ob[(size_t)row*(NHEAD*HID) + h*HID + ct*16 + c] = f2bf(v);
        }
      }
    } else {
      float* ob = (float*)outp + (size_t)blockIdx.y * NN * 64;
      #pragma unroll
      for (int r = 0; r < 4; ++r){
        int row = i0 + rH*16 + g*4 + r;
        #pragma unroll
        for (int ct = 0; ct < NCT; ++ct)
          ob[(size_t)row*64 + ct*16 + c] = acc[ct][r];
        if (c == 0) ob[(size_t)row*64 + 48] = accs[r];
      }
    }
  }
}

// ---------------- gemm2: WhT2[c][n] bf16 = (h_bf16 @ W_out)^T ; s2/d2/bd2 fused ----------------
__global__ __launch_bounds__(256) void gemm2_k(const unsigned short* __restrict__ hb,
    const unsigned short* __restrict__ WoT, const float* __restrict__ aos, const float* __restrict__ aod,
    unsigned short* __restrict__ WhT2, float* __restrict__ s2, float* __restrict__ d2,
    float2* __restrict__ bd2){
  __shared__ unsigned short aS[64*64];
  __shared__ unsigned short bS[48*64];
  const int t = threadIdx.x, l = t & 63, wv = t >> 6, g = l >> 4, c = l & 15;
  const int n0 = blockIdx.x * 64;
  f32x4 acc[3] = {};
  for (int k0 = 0; k0 < NHEAD*HID; k0 += 64){
    __syncthreads();
    #pragma unroll
    for (int p = 0; p < 2; ++p){
      int u = t + p*256, o = u >> 3, ch = u & 7;
      *(s16x8*)&aS[SWZ(o, ch*8)] = *(const s16x8*)&hb[(size_t)(n0+o)*(NHEAD*HID) + k0 + ch*8];
    }
    for (int u = t; u < 384; u += 256){
      int o = u >> 3, ch = u & 7;
      *(s16x8*)&bS[SWZ(o, ch*8)] = *(const s16x8*)&WoT[(size_t)o*(NHEAD*HID) + k0 + ch*8];
    }
    __syncthreads();
    #pragma unroll
    for (int ks = 0; ks < 2; ++ks){
      s16x8 av = *(const s16x8*)&aS[SWZ(wv*16 + c, ks*32 + g*8)];
      #pragma unroll
      for (int ct = 0; ct < 3; ++ct){
        s16x8 bv = *(const s16x8*)&bS[SWZ(ct*16 + c, ks*32 + g*8)];
        acc[ct] = __builtin_amdgcn_mfma_f32_16x16x32_bf16(av, bv, acc[ct], 0, 0, 0);
      }
    }
  }
  float asv[3], adv[3];
  #pragma unroll
  for (int ct = 0; ct < 3; ++ct){
    int col = ct*16 + c;
    asv[ct] = (col < NCLS) ? aos[col] : 0.f;
    adv[ct] = (col < NCLS) ? aod[col] : 0.f;
  }
  #pragma unroll
  for (int r = 0; r < 4; ++r){
    float ps = acc[0][r]*asv[0] + acc[1][r]*asv[1] + acc[2][r]*asv[2];
    float pd = acc[0][r]*adv[0] + acc[1][r]*adv[1] + acc[2][r]*adv[2];
    #pragma unroll
    for (int off = 1; off < 16; off <<= 1){ ps += __shfl_xor(ps, off); pd += __shfl_xor(pd, off); }
    if (c == 0){
      int n = n0 + wv*16 + g*4 + r;
      s2[n] = ps; d2[n] = pd;
      bd2[n] = make_float2(exp2f(pd*LOG2E), exp2f(0.2f*pd*LOG2E));
    }
  }
  __syncthreads();
  #pragma unroll
  for (int ct = 0; ct < 3; ++ct)
    *(uint2*)&bS[SWZ(ct*16 + c, wv*16 + g*4)] = make_uint2(cvtpk(acc[ct][0], acc[ct][1]), cvtpk(acc[ct][2], acc[ct][3]));
  __syncthreads();
  for (int u = t; u < 384; u += 256){
    int o = u >> 3, ch = u & 7;
    *(s16x8*)&WhT2[(size_t)o*NN + n0 + ch*8] = *(const s16x8*)&bS[SWZ(o, ch*8)];
  }
}

// ---------------- merge 8 chunks + elu + row log_softmax ----------------
__global__ __launch_bounds__(256) void final_k(const float* __restrict__ part, float* __restrict__ out){
  const int wid = (blockIdx.x*256 + threadIdx.x) >> 6;
  const int c = threadIdx.x & 63;
  float acc = 0.f, rs = 0.f;
  #pragma unroll
  for (int ch = 0; ch < 8; ++ch){
    const float* pb = part + ((size_t)ch*NN + wid)*64;
    if (c < 48) acc += pb[c];
    rs += pb[48];
  }
  float v = acc / fmaxf(rs, 1e-30f);
  float e = v > 0.f ? v : __expf(v) - 1.f;
  float ev = (c < NCLS) ? e : -3.0e38f;
  float m = ev;
  #pragma unroll
  for (int off = 32; off; off >>= 1) m = fmaxf(m, __shfl_xor(m, off));
  float ex = (c < NCLS) ? __expf(e - m) : 0.f;
  float s = ex;
  #pragma unroll
  for (int off = 32; off; off >>= 1) s += __shfl_xor(s, off);
  if (c < NCLS) out[(size_t)wid*NCLS + c] = e - m - __logf(s);
}

extern "C" void kernel_launch(void* const* d_in, const int* in_sizes, int n_in,
                              void* d_out, int out_size, void* d_ws, size_t ws_size,
                              hipStream_t stream){
  (void)in_sizes; (void)n_in; (void)out_size; (void)ws_size;
  const float* x     = (const float*)d_in[0];
  const int*   adj   = (const int*)  d_in[1];
  const float* W     = (const float*)d_in[2];
  const float* a_src = (const float*)d_in[3];
  const float* a_dst = (const float*)d_in[4];
  const float* W_out = (const float*)d_in[5];
  const float* aos   = (const float*)d_in[6];
  const float* aod   = (const float*)d_in[7];
  float* out = (float*)d_out;

  char* p = (char*)d_ws;
  unsigned* bmT        = (unsigned*)p;       p += (size_t)NN*128*4;            // 2 MB
  unsigned short* WbT  = (unsigned short*)p; p += (size_t)NHEAD*HID*F_IN*2;    // 1 MB
  unsigned short* WhT  = (unsigned short*)p; p += (size_t)NHEAD*HID*NN*2;      // 4 MB
  unsigned short* hbuf = (unsigned short*)p; p += (size_t)NN*NHEAD*HID*2;      // 4 MB
  unsigned short* WoT  = (unsigned short*)p; p += (size_t)48*NHEAD*HID*2;      // 48 KB
  unsigned short* WhT2 = (unsigned short*)p; p += (size_t)48*NN*2;             // 384 KB
  float* srcv = (float*)p; p += (size_t)NHEAD*NN*4;
  float* dstv = (float*)p; p += (size_t)NHEAD*NN*4;
  float* maxd = (float*)p; p += 256;
  float* s2   = (float*)p; p += (size_t)NN*4;
  float* d2   = (float*)p; p += (size_t)NN*4;
  float* m2   = (float*)p; p += 256;
  float2* bdv1 = (float2*)p; p += (size_t)NHEAD*NN*8;                          // 256 KB
  float2* bdv2 = (float2*)p; p += (size_t)NN*8;                                // 32 KB
  float* part = (float*)p; p += (size_t)8*NN*64*4;                             // 8 MB

  pack_adj_k<<<(NN*NN)/256, 256, 0, stream>>>(adj, bmT);
  cast_W_k<<<dim3(F_IN/64, NHEAD), 256, 0, stream>>>(W, WbT);
  cast_Wo_k<<<96, 256, 0, stream>>>(W_out, WoT);
  gemm1_k<<<dim3(NN/64, NHEAD), 256, 0, stream>>>(x, WbT, WhT, a_src, a_dst, srcv, dstv, bdv1);
  maxred_k<<<NHEAD, 256, 0, stream>>>(dstv, maxd);
  agg_mfma_k<4, 64, false, true><<<dim3(NN/32, NHEAD), 256, 0, stream>>>(bmT, WhT, srcv, bdv1, maxd, hbuf);
  gemm2_k<<<NN/64, 256, 0, stream>>>(hbuf, WoT, aos, aod, WhT2, s2, d2, bdv2);
  maxred_k<<<1, 256, 0, stream>>>(d2, m2);
  agg_mfma_k<3, 8, true, false><<<dim3(NN/32, 8), 256, 0, stream>>>(bmT, WhT2, s2, bdv2, m2, part);
  final_k<<<NN/4, 256, 0, stream>>>(part, out);
}

// Round 13
// 162.002 us; speedup vs baseline: 1.3010x; 1.0083x over previous
//
#include <hip/hip_runtime.h>

#define NN 4096
#define F_IN 1024
#define NHEAD 8
#define HID 64
#define NCLS 40
#define LOG2E 1.44269504f

typedef float f32x4 __attribute__((ext_vector_type(4)));
typedef float f32x2 __attribute__((ext_vector_type(2)));
typedef short s16x8 __attribute__((ext_vector_type(8)));

// XOR-swizzled halfword index within a [R][64]-hw (128B-row) LDS tile.
#define SWZ(r,c) (((r)*64) + ((c) ^ (((r)&7)<<3)))

__device__ __forceinline__ unsigned short f2bf(float f){  // RNE float->bf16
  unsigned u = __float_as_uint(f);
  return (unsigned short)((u + 0x7fffu + ((u >> 16) & 1u)) >> 16);
}
__device__ __forceinline__ unsigned cvtpk(float lo, float hi){  // packed bf16 pair
  unsigned r; asm("v_cvt_pk_bf16_f32 %0, %1, %2" : "=v"(r) : "v"(lo), "v"(hi)); return r;
}
__device__ __forceinline__ f32x2 pkmul(f32x2 a, f32x2 b){  // packed fp32 dual mul
  f32x2 r; asm("v_pk_mul_f32 %0, %1, %2" : "=v"(r) : "v"(a), "v"(b)); return r;
}

// ---------------- pack adjacency -> word-transposed bitmask ----------------
__global__ __launch_bounds__(256) void pack_adj_k(const int* __restrict__ adj, unsigned* __restrict__ bmT){
  int gid = blockIdx.x*256 + threadIdx.x;
  int lane = threadIdx.x & 63;
  unsigned long long m = __ballot(adj[gid] > 0);
  int w = gid >> 5, i = w >> 7, jw = w & 127;
  if (lane == 0)       bmT[(size_t)jw*NN + i] = (unsigned)m;
  else if (lane == 32) bmT[(size_t)jw*NN + i] = (unsigned)(m >> 32);
}

// ---------------- WbT[h][o][k] = bf16(W[h][k][o]) ----------------
__global__ __launch_bounds__(256) void cast_W_k(const float* __restrict__ W, unsigned short* __restrict__ WbT){
  __shared__ float T[64][65];
  const int h = blockIdx.y, k0 = blockIdx.x*64, t = threadIdx.x;
  for (int idx = t; idx < 1024; idx += 256){
    int k = idx >> 4, c4 = idx & 15;
    *(float4*)&T[k][c4*4] = *(const float4*)&W[((size_t)h*F_IN + k0 + k)*HID + c4*4];
  }
  __syncthreads();
  for (int idx = t; idx < 512; idx += 256){
    int o = idx >> 3, ch = idx & 7;
    s16x8 v;
    #pragma unroll
    for (int e = 0; e < 8; ++e) v[e] = (short)f2bf(T[ch*8 + e][o]);
    *(s16x8*)&WbT[((size_t)h*HID + o)*F_IN + k0 + ch*8] = v;
  }
}

// ---------------- WoT[c][k] = bf16(W_out[k][c]), rows 40..47 zero ----------------
__global__ __launch_bounds__(256) void cast_Wo_k(const float* __restrict__ Wout, unsigned short* __restrict__ WoT){
  int idx = blockIdx.x*256 + threadIdx.x;   // 48*512
  int cc = idx >> 9, k = idx & 511;
  WoT[idx] = (cc < NCLS) ? f2bf(Wout[(size_t)k*NCLS + cc]) : (unsigned short)0;
}

// ---------------- gemm1: WhT[h][o][n] bf16 = (x@W)^T ; srcv/dstv/bdv fused epilogue ----------------
__global__ __launch_bounds__(256) void gemm1_k(const float* __restrict__ x,
    const unsigned short* __restrict__ WbT, unsigned short* __restrict__ WhT,
    const float* __restrict__ a_src, const float* __restrict__ a_dst,
    float* __restrict__ srcv, float* __restrict__ dstv, float2* __restrict__ bdv){
  __shared__ unsigned short xS[64*64];
  __shared__ unsigned short wS[64*64];
  const int t = threadIdx.x, l = t & 63, wv = t >> 6, g = l >> 4, c = l & 15;
  const int h = blockIdx.y, n0 = blockIdx.x * 64;
  f32x4 acc[4] = {};
  for (int k0 = 0; k0 < F_IN; k0 += 64){
    __syncthreads();
    #pragma unroll
    for (int p = 0; p < 4; ++p){
      int idx = t + p*256, row = idx >> 4, c4 = idx & 15;
      float4 v = *(const float4*)&x[(size_t)(n0+row)*F_IN + k0 + c4*4];
      *(uint2*)&xS[SWZ(row, c4*4)] = make_uint2(cvtpk(v.x, v.y), cvtpk(v.z, v.w));
    }
    #pragma unroll
    for (int p = 0; p < 2; ++p){
      int idx = t + p*256, o = idx >> 3, ch = idx & 7;
      *(s16x8*)&wS[SWZ(o, ch*8)] = *(const s16x8*)&WbT[(size_t)(h*HID + o)*F_IN + k0 + ch*8];
    }
    __syncthreads();
    #pragma unroll
    for (int ks = 0; ks < 2; ++ks){
      s16x8 av = *(const s16x8*)&xS[SWZ(wv*16 + c, ks*32 + g*8)];
      #pragma unroll
      for (int ct = 0; ct < 4; ++ct){
        s16x8 bv = *(const s16x8*)&wS[SWZ(ct*16 + c, ks*32 + g*8)];
        acc[ct] = __builtin_amdgcn_mfma_f32_16x16x32_bf16(av, bv, acc[ct], 0, 0, 0);
      }
    }
  }
  float asv[4], adv[4];
  #pragma unroll
  for (int ct = 0; ct < 4; ++ct){ asv[ct] = a_src[h*HID + ct*16 + c]; adv[ct] = a_dst[h*HID + ct*16 + c]; }
  #pragma unroll
  for (int r = 0; r < 4; ++r){
    float ps = acc[0][r]*asv[0] + acc[1][r]*asv[1] + acc[2][r]*asv[2] + acc[3][r]*asv[3];
    float pd = acc[0][r]*adv[0] + acc[1][r]*adv[1] + acc[2][r]*adv[2] + acc[3][r]*adv[3];
    #pragma unroll
    for (int off = 1; off < 16; off <<= 1){ ps += __shfl_xor(ps, off); pd += __shfl_xor(pd, off); }
    if (c == 0){
      int n = n0 + wv*16 + g*4 + r;
      srcv[h*NN + n] = ps; dstv[h*NN + n] = pd;
      bdv[h*NN + n] = make_float2(exp2f(pd*LOG2E), exp2f(0.2f*pd*LOG2E));
    }
  }
  __syncthreads();
  #pragma unroll
  for (int ct = 0; ct < 4; ++ct)
    *(uint2*)&xS[SWZ(ct*16 + c, wv*16 + g*4)] = make_uint2(cvtpk(acc[ct][0], acc[ct][1]), cvtpk(acc[ct][2], acc[ct][3]));
  __syncthreads();
  #pragma unroll
  for (int p = 0; p < 2; ++p){
    int idx = t + p*256, o = idx >> 3, ch = idx & 7;
    *(s16x8*)&WhT[(size_t)(h*HID + o)*NN + n0 + ch*8] = *(const s16x8*)&xS[SWZ(o, ch*8)];
  }
}

// ---------------- per-4096-segment max reduce ----------------
__global__ __launch_bounds__(256) void maxred_k(const float* __restrict__ in, float* __restrict__ out){
  __shared__ float red[4];
  const float* p = in + (size_t)blockIdx.x*NN;
  float m = -3.0e38f;
  for (int i = threadIdx.x; i < NN; i += 256) m = fmaxf(m, p[i]);
  #pragma unroll
  for (int off = 32; off; off >>= 1) m = fmaxf(m, __shfl_xor(m, off));
  if ((threadIdx.x & 63) == 0) red[threadIdx.x >> 6] = m;
  __syncthreads();
  if (threadIdx.x == 0) out[blockIdx.x] = fmaxf(fmaxf(red[0], red[1]), fmaxf(red[2], red[3]));
}

// ---------------- MFMA masked-softmax aggregate (r8 ping-pong skeleton, bdv-staged) ----------------
// Block: 32 rows; 4 waves = j-parity tl(2) x row-half rH(2).
// Per iteration: loadRegs(next) -> computeBuf(cur) -> writeLDS(cur^1) -> one barrier.
// (B,D) precomputed in gemm epilogues (bdv), staged via LDS like r8 (no exp2f here).
// p_ij = bit * med3(A_i*B_j, C_i*D_j, 1). Row sums via ones-MFMA.
// MODE 0: L1 chunked (blockIdx.y = h*2+ck) -> fp32 partials [ck][row][512] + den[(ck*8+h)*NN+row]
// MODE 1: L2 chunked (blockIdx.y = ck)     -> fp32 partials [ck][row][64], den in col 48
template<int NCT, int NJT, int MODE>
__global__ __launch_bounds__(256) void agg_mfma_k(
    const unsigned* __restrict__ bmT, const unsigned short* __restrict__ VT,
    const float* __restrict__ srcv, const float2* __restrict__ bdv,
    const float* __restrict__ maxp, float* __restrict__ partOut, float* __restrict__ denOut)
{
  __shared__ unsigned short vS[2][2][NCT*16*64];
  __shared__ float2 dS[2][2][64];
  __shared__ unsigned bitS[2][2][2][32];
  const int t = threadIdx.x, l = t & 63, wv = t >> 6, g = l >> 4, c = l & 15;
  const int h  = (MODE == 0) ? (blockIdx.y >> 1) : 0;
  const int ck = (MODE == 0) ? (blockIdx.y & 1)  : blockIdx.y;
  const int jt0 = ck * NJT;
  const int i0 = blockIdx.x * 32;
  const int tl = wv >> 1, rH = wv & 1;
  const int lr = rH*16 + c;
  const float sr = srcv[h*NN + i0 + lr];
  const float mx = maxp[MODE == 0 ? h : 0];
  const float tm = sr + mx;
  const float mi2 = fmaxf(tm, 0.2f*tm) * LOG2E;
  f32x2 ac2;
  ac2[0] = exp2f(fmaf(sr, LOG2E, -mi2));        // A_i
  ac2[1] = exp2f(fmaf(0.2f*sr, LOG2E, -mi2));   // C_i
  const unsigned short* vb = VT + (MODE == 0 ? (size_t)h*HID*NN : (size_t)0);
  const float2* bp = bdv + (MODE == 0 ? (size_t)h*NN : (size_t)0);

  f32x4 acc[NCT] = {};
  f32x4 accs = {};
  s16x8 ones;
  #pragma unroll
  for (int e = 0; e < 8; ++e) ones[e] = (short)0x3F80;

  s16x8 vreg[NCT]; float2 dreg = make_float2(0.f, 0.f); unsigned breg = 0;
  auto loadRegs = [&](int jt){
    #pragma unroll
    for (int p = 0; p < NCT; ++p){
      int u = t + p*256;
      int tt = u / (NCT*128), rem = u % (NCT*128);
      int o = rem >> 3, chk = rem & 7;
      vreg[p] = *(const s16x8*)&vb[(size_t)o*NN + (jt+tt)*64 + chk*8];
    }
    if (t < 128){
      f32x2 bd = *(const f32x2*)&bp[(jt + (t>>6))*64 + (t&63)];
      dreg = make_float2(bd[0], bd[1]);
    }
    else { int u = t - 128; breg = bmT[(size_t)((jt + (u>>6))*2 + ((u>>5)&1))*NN + i0 + (u&31)]; }
  };
  auto writeLDS = [&](int b){
    #pragma unroll
    for (int p = 0; p < NCT; ++p){
      int u = t + p*256;
      int tt = u / (NCT*128), rem = u % (NCT*128);
      int o = rem >> 3, chk = rem & 7;
      *(s16x8*)&vS[b][tt][SWZ(o, chk*8)] = vreg[p];
    }
    if (t < 128) dS[b][t>>6][t&63] = dreg;
    else { int u = t - 128; bitS[b][u>>6][(u>>5)&1][u&31] = breg; }
  };
  auto computeBuf = [&](int b){
    #pragma unroll
    for (int ks = 0; ks < 2; ++ks){
      unsigned wb = (bitS[b][tl][ks][lr] >> (g*8)) & 0xffu;
      const f32x2* dr = (const f32x2*)&dS[b][tl][ks*32 + g*8];
      float q[8];
      #pragma unroll
      for (int e = 0; e < 8; ++e){
        f32x2 pr = pkmul(ac2, dr[e]);
        float m3 = __builtin_amdgcn_fmed3f(pr[0], pr[1], 1.0f);
        q[e] = (wb & (1u << e)) ? m3 : 0.f;
      }
      s16x8 afr;
      ((unsigned*)&afr)[0] = cvtpk(q[0], q[1]);
      ((unsigned*)&afr)[1] = cvtpk(q[2], q[3]);
      ((unsigned*)&afr)[2] = cvtpk(q[4], q[5]);
      ((unsigned*)&afr)[3] = cvtpk(q[6], q[7]);
      #pragma unroll
      for (int ct = 0; ct < NCT; ++ct){
        s16x8 bv = *(const s16x8*)&vS[b][tl][SWZ(ct*16 + c, ks*32 + g*8)];
        acc[ct] = __builtin_amdgcn_mfma_f32_16x16x32_bf16(afr, bv, acc[ct], 0, 0, 0);
      }
      accs = __builtin_amdgcn_mfma_f32_16x16x32_bf16(afr, ones, accs, 0, 0, 0);
    }
  };

  // prologue: stage first pair into buf 0
  loadRegs(jt0);
  writeLDS(0);
  __syncthreads();
  int cur = 0;
  for (int jj = 0; jj < NJT; jj += 2){
    const bool more = (jj + 2 < NJT);
    if (more) loadRegs(jt0 + jj + 2);   // issue next-pair loads early
    computeBuf(cur);                    // consume own-parity tile
    if (more) writeLDS(cur ^ 1);        // write-late into other buffer
    __syncthreads();                    // single barrier per iteration
    cur ^= 1;
  }

  // merge j-parity wave pairs via LDS (aliases vS)
  float* mrg = (float*)&vS[0][0][0];
  constexpr int S = (NCT + 1) * 4;
  if (tl == 1){
    int base = (rH*64 + l) * S;
    #pragma unroll
    for (int ct = 0; ct < NCT; ++ct)
      #pragma unroll
      for (int r = 0; r < 4; ++r) mrg[base + ct*4 + r] = acc[ct][r];
    #pragma unroll
    for (int r = 0; r < 4; ++r) mrg[base + NCT*4 + r] = accs[r];
  }
  __syncthreads();
  if (tl == 0){
    int base = (rH*64 + l) * S;
    #pragma unroll
    for (int ct = 0; ct < NCT; ++ct)
      #pragma unroll
      for (int r = 0; r < 4; ++r) acc[ct][r] += mrg[base + ct*4 + r];
    #pragma unroll
    for (int r = 0; r < 4; ++r) accs[r] += mrg[base + NCT*4 + r];
    if (MODE == 0){
      float* ob = partOut + (size_t)ck * NN * (NHEAD*HID);
      #pragma unroll
      for (int r = 0; r < 4; ++r){
        int row = i0 + rH*16 + g*4 + r;
        #pragma unroll
        for (int ct = 0; ct < NCT; ++ct)
          ob[(size_t)row*(NHEAD*HID) + h*HID + ct*16 + c] = acc[ct][r];
        if (c == 0) denOut[(size_t)(ck*NHEAD + h)*NN + row] = accs[r];
      }
    } else {
      float* ob = partOut + (size_t)ck * NN * 64;
      #pragma unroll
      for (int r = 0; r < 4; ++r){
        int row = i0 + rH*16 + g*4 + r;
        #pragma unroll
        for (int ct = 0; ct < NCT; ++ct)
          ob[(size_t)row*64 + ct*16 + c] = acc[ct][r];
        if (c == 0) ob[(size_t)row*64 + 48] = accs[r];
      }
    }
  }
}

// ---------------- layer-1 merge: 2 chunks -> normalize -> elu -> bf16 hbuf ----------------
__global__ __launch_bounds__(256) void merge1_k(const float* __restrict__ part, const float* __restrict__ den,
                                                unsigned short* __restrict__ hb){
  int idx = blockIdx.x*256 + threadIdx.x;   // NN*128 threads total
  int row = idx >> 7, q = idx & 127;
  float4 a = *(const float4*)&part[(size_t)row*(NHEAD*HID) + q*4];
  float4 b = *(const float4*)&part[((size_t)NN + row)*(NHEAD*HID) + q*4];
  int h = q >> 4;
  float dn = den[(size_t)h*NN + row] + den[(size_t)(NHEAD + h)*NN + row];
  float inv = 1.f / fmaxf(dn, 1e-30f);
  float v0 = (a.x + b.x)*inv, v1 = (a.y + b.y)*inv, v2 = (a.z + b.z)*inv, v3 = (a.w + b.w)*inv;
  v0 = v0 > 0.f ? v0 : __expf(v0) - 1.f;
  v1 = v1 > 0.f ? v1 : __expf(v1) - 1.f;
  v2 = v2 > 0.f ? v2 : __expf(v2) - 1.f;
  v3 = v3 > 0.f ? v3 : __expf(v3) - 1.f;
  *(uint2*)&hb[(size_t)row*(NHEAD*HID) + q*4] = make_uint2(cvtpk(v0, v1), cvtpk(v2, v3));
}

// ---------------- gemm2: WhT2[c][n] bf16 = (h_bf16 @ W_out)^T ; s2/d2/bd2 fused ----------------
__global__ __launch_bounds__(256) void gemm2_k(const unsigned short* __restrict__ hb,
    const unsigned short* __restrict__ WoT, const float* __restrict__ aos, const float* __restrict__ aod,
    unsigned short* __restrict__ WhT2, float* __restrict__ s2, float* __restrict__ d2,
    float2* __restrict__ bd2){
  __shared__ unsigned short aS[64*64];
  __shared__ unsigned short bS[48*64];
  const int t = threadIdx.x, l = t & 63, wv = t >> 6, g = l >> 4, c = l & 15;
  const int n0 = blockIdx.x * 64;
  f32x4 acc[3] = {};
  for (int k0 = 0; k0 < NHEAD*HID; k0 += 64){
    __syncthreads();
    #pragma unroll
    for (int p = 0; p < 2; ++p){
      int u = t + p*256, o = u >> 3, ch = u & 7;
      *(s16x8*)&aS[SWZ(o, ch*8)] = *(const s16x8*)&hb[(size_t)(n0+o)*(NHEAD*HID) + k0 + ch*8];
    }
    for (int u = t; u < 384; u += 256){
      int o = u >> 3, ch = u & 7;
      *(s16x8*)&bS[SWZ(o, ch*8)] = *(const s16x8*)&WoT[(size_t)o*(NHEAD*HID) + k0 + ch*8];
    }
    __syncthreads();
    #pragma unroll
    for (int ks = 0; ks < 2; ++ks){
      s16x8 av = *(const s16x8*)&aS[SWZ(wv*16 + c, ks*32 + g*8)];
      #pragma unroll
      for (int ct = 0; ct < 3; ++ct){
        s16x8 bv = *(const s16x8*)&bS[SWZ(ct*16 + c, ks*32 + g*8)];
        acc[ct] = __builtin_amdgcn_mfma_f32_16x16x32_bf16(av, bv, acc[ct], 0, 0, 0);
      }
    }
  }
  float asv[3], adv[3];
  #pragma unroll
  for (int ct = 0; ct < 3; ++ct){
    int col = ct*16 + c;
    asv[ct] = (col < NCLS) ? aos[col] : 0.f;
    adv[ct] = (col < NCLS) ? aod[col] : 0.f;
  }
  #pragma unroll
  for (int r = 0; r < 4; ++r){
    float ps = acc[0][r]*asv[0] + acc[1][r]*asv[1] + acc[2][r]*asv[2];
    float pd = acc[0][r]*adv[0] + acc[1][r]*adv[1] + acc[2][r]*adv[2];
    #pragma unroll
    for (int off = 1; off < 16; off <<= 1){ ps += __shfl_xor(ps, off); pd += __shfl_xor(pd, off); }
    if (c == 0){
      int n = n0 + wv*16 + g*4 + r;
      s2[n] = ps; d2[n] = pd;
      bd2[n] = make_float2(exp2f(pd*LOG2E), exp2f(0.2f*pd*LOG2E));
    }
  }
  __syncthreads();
  #pragma unroll
  for (int ct = 0; ct < 3; ++ct)
    *(uint2*)&bS[SWZ(ct*16 + c, wv*16 + g*4)] = make_uint2(cvtpk(acc[ct][0], acc[ct][1]), cvtpk(acc[ct][2], acc[ct][3]));
  __syncthreads();
  for (int u = t; u < 384; u += 256){
    int o = u >> 3, ch = u & 7;
    *(s16x8*)&WhT2[(size_t)o*NN + n0 + ch*8] = *(const s16x8*)&bS[SWZ(o, ch*8)];
  }
}

// ---------------- merge 8 chunks + elu + row log_softmax ----------------
__global__ __launch_bounds__(256) void final_k(const float* __restrict__ part, float* __restrict__ out){
  const int wid = (blockIdx.x*256 + threadIdx.x) >> 6;
  const int c = threadIdx.x & 63;
  float acc = 0.f, rs = 0.f;
  #pragma unroll
  for (int ch = 0; ch < 8; ++ch){
    const float* pb = part + ((size_t)ch*NN + wid)*64;
    if (c < 48) acc += pb[c];
    rs += pb[48];
  }
  float v = acc / fmaxf(rs, 1e-30f);
  float e = v > 0.f ? v : __expf(v) - 1.f;
  float ev = (c < NCLS) ? e : -3.0e38f;
  float m = ev;
  #pragma unroll
  for (int off = 32; off; off >>= 1) m = fmaxf(m, __shfl_xor(m, off));
  float ex = (c < NCLS) ? __expf(e - m) : 0.f;
  float s = ex;
  #pragma unroll
  for (int off = 32; off; off >>= 1) s += __shfl_xor(s, off);
  if (c < NCLS) out[(size_t)wid*NCLS + c] = e - m - __logf(s);
}

extern "C" void kernel_launch(void* const* d_in, const int* in_sizes, int n_in,
                              void* d_out, int out_size, void* d_ws, size_t ws_size,
                              hipStream_t stream){
  (void)in_sizes; (void)n_in; (void)out_size; (void)ws_size;
  const float* x     = (const float*)d_in[0];
  const int*   adj   = (const int*)  d_in[1];
  const float* W     = (const float*)d_in[2];
  const float* a_src = (const float*)d_in[3];
  const float* a_dst = (const float*)d_in[4];
  const float* W_out = (const float*)d_in[5];
  const float* aos   = (const float*)d_in[6];
  const float* aod   = (const float*)d_in[7];
  float* out = (float*)d_out;

  char* p = (char*)d_ws;
  unsigned* bmT        = (unsigned*)p;       p += (size_t)NN*128*4;            // 2 MB
  unsigned short* WbT  = (unsigned short*)p; p += (size_t)NHEAD*HID*F_IN*2;    // 1 MB
  unsigned short* WhT  = (unsigned short*)p; p += (size_t)NHEAD*HID*NN*2;      // 4 MB
  unsigned short* hbuf = (unsigned short*)p; p += (size_t)NN*NHEAD*HID*2;      // 4 MB
  unsigned short* WoT  = (unsigned short*)p; p += (size_t)48*NHEAD*HID*2;      // 48 KB
  unsigned short* WhT2 = (unsigned short*)p; p += (size_t)48*NN*2;             // 384 KB
  float* srcv = (float*)p; p += (size_t)NHEAD*NN*4;
  float* dstv = (float*)p; p += (size_t)NHEAD*NN*4;
  float* maxd = (float*)p; p += 256;
  float* s2   = (float*)p; p += (size_t)NN*4;
  float* d2   = (float*)p; p += (size_t)NN*4;
  float* m2   = (float*)p; p += 256;
  float2* bdv1 = (float2*)p; p += (size_t)NHEAD*NN*8;                          // 256 KB
  float2* bdv2 = (float2*)p; p += (size_t)NN*8;                                // 32 KB
  float* den1 = (float*)p; p += (size_t)2*NHEAD*NN*4;                          // 256 KB
  float* partU = (float*)p; p += (size_t)2*NN*NHEAD*HID*4;                     // 16 MB (L1 2-chunk / L2 8-chunk partials)

  pack_adj_k<<<(NN*NN)/256, 256, 0, stream>>>(adj, bmT);
  cast_W_k<<<dim3(F_IN/64, NHEAD), 256, 0, stream>>>(W, WbT);
  cast_Wo_k<<<96, 256, 0, stream>>>(W_out, WoT);
  gemm1_k<<<dim3(NN/64, NHEAD), 256, 0, stream>>>(x, WbT, WhT, a_src, a_dst, srcv, dstv, bdv1);
  maxred_k<<<NHEAD, 256, 0, stream>>>(dstv, maxd);
  agg_mfma_k<4, 32, 0><<<dim3(NN/32, 16), 256, 0, stream>>>(bmT, WhT, srcv, bdv1, maxd, partU, den1);
  merge1_k<<<(NN*128)/256, 256, 0, stream>>>(partU, den1, hbuf);
  gemm2_k<<<NN/64, 256, 0, stream>>>(hbuf, WoT, aos, aod, WhT2, s2, d2, bdv2);
  maxred_k<<<1, 256, 0, stream>>>(d2, m2);
  agg_mfma_k<3, 8, 1><<<dim3(NN/32, 8), 256, 0, stream>>>(bmT, WhT2, s2, bdv2, m2, partU, nullptr);
  final_k<<<NN/4, 256, 0, stream>>>(partU, out);
}